// Round 4
// baseline (48.504 us; speedup 1.0000x reference)
//
#include <hip/hip_runtime.h>

namespace {

constexpr float ETA_C = 1.5f;
constexpr float PI_F  = 3.14159265358979323846f;
constexpr int   BLOCK = 256;

typedef float f32x4 __attribute__((ext_vector_type(4)));  // native vector for nontemporal builtins

__device__ __forceinline__ float fast_rcp(float x)  { return __builtin_amdgcn_rcpf(x); }
__device__ __forceinline__ float fast_sqrt(float x) { return __builtin_amdgcn_sqrtf(x); }
__device__ __forceinline__ float fast_rsq(float x)  { return __builtin_amdgcn_rsqf(x); }

__device__ __forceinline__ float schlick_w(float c) {
    float m = fminf(fmaxf(1.0f - c, 0.0f), 1.0f);
    float m2 = m * m;
    return m2 * m2 * m;  // m^5
}

// min-waves-per-EU = 4 -> VGPR cap 128: enough to keep all 12 float4 loads
// in flight (48 payload VGPRs) with a single waitcnt at first use.
// (256,8) forced VGPR=32 and serialized the loads -> latency-bound at 46us.
__global__ __launch_bounds__(BLOCK, 4) void renderer_kernel(
    const float* __restrict__ light_p,
    const float* __restrict__ dist_p,
    const float* __restrict__ norm_p,
    const float* __restrict__ view_p,
    const float* __restrict__ anis_p,
    const float* __restrict__ rough_p,
    const float* __restrict__ met_p,
    const float* __restrict__ tint_p,
    const float* __restrict__ salb_p,
    const float* __restrict__ dalb_p,
    float* __restrict__ out_p,
    int n_pts)
{
    const int t = blockIdx.x * BLOCK + threadIdx.x;   // one thread = 4 points
    if (t * 4 >= n_pts) return;

    const float light = light_p[0];

    // ---- vectorized loads: 4 points per thread, all float4-aligned ----
    const f32x4 dv = reinterpret_cast<const f32x4*>(dist_p)[t];
    const f32x4 av = reinterpret_cast<const f32x4*>(anis_p)[t];
    const f32x4 rv = reinterpret_cast<const f32x4*>(rough_p)[t];
    const f32x4 mv = reinterpret_cast<const f32x4*>(met_p)[t];
    const f32x4 tv = reinterpret_cast<const f32x4*>(tint_p)[t];

    const f32x4* n4 = reinterpret_cast<const f32x4*>(norm_p) + 3 * t;
    const f32x4 n0 = n4[0], n1 = n4[1], n2 = n4[2];
    const f32x4* v4 = reinterpret_cast<const f32x4*>(view_p) + 3 * t;
    const f32x4 v0 = v4[0], v1 = v4[1], v2 = v4[2];
    const f32x4* s4 = reinterpret_cast<const f32x4*>(salb_p) + 3 * t;
    const f32x4 s0 = s4[0], s1 = s4[1], s2 = s4[2];
    const f32x4* b4 = reinterpret_cast<const f32x4*>(dalb_p) + 3 * t;
    const f32x4 b0 = b4[0], b1 = b4[1], b2 = b4[2];

    const float dist[4]  = {dv.x, dv.y, dv.z, dv.w};
    const float anv[4]   = {av.x, av.y, av.z, av.w};
    const float rgv[4]   = {rv.x, rv.y, rv.z, rv.w};
    const float mtv[4]   = {mv.x, mv.y, mv.z, mv.w};
    const float ttv[4]   = {tv.x, tv.y, tv.z, tv.w};

    const float nx[4] = {n0.x, n0.w, n1.z, n2.y};
    const float ny[4] = {n0.y, n1.x, n1.w, n2.z};
    const float nz[4] = {n0.z, n1.y, n2.x, n2.w};
    const float vx[4] = {v0.x, v0.w, v1.z, v2.y};
    const float vy[4] = {v0.y, v1.x, v1.w, v2.z};
    const float vz[4] = {v0.z, v1.y, v2.x, v2.w};
    const float sx[4] = {s0.x, s0.w, s1.z, s2.y};
    const float sy[4] = {s0.y, s1.x, s1.w, s2.z};
    const float sz[4] = {s0.z, s1.y, s2.x, s2.w};
    const float bx[4] = {b0.x, b0.w, b1.z, b2.y};
    const float by[4] = {b0.y, b1.x, b1.w, b2.z};
    const float bz[4] = {b0.z, b1.y, b2.x, b2.w};

    float ox[4], oy[4], oz[4];

#pragma unroll
    for (int j = 0; j < 4; ++j) {
        const float cosv = nx[j] * vx[j] + ny[j] * vy[j] + nz[j] * vz[j];
        const float anis  = fmaxf(anv[j], 1e-5f);
        const float rough = fmaxf(rgv[j], 1e-5f);
        const float met   = fmaxf(mtv[j], 1e-5f);
        const float tint  = fmaxf(ttv[j], 1e-6f);
        const float sa[3] = {fmaxf(sx[j], 1e-5f), fmaxf(sy[j], 1e-5f), fmaxf(sz[j], 1e-5f)};
        const float da[3] = {fmaxf(bx[j], 1e-5f), fmaxf(by[j], 1e-5f), fmaxf(bz[j], 1e-5f)};

        const float c2 = cosv * cosv;
        const float ci = fabsf(cosv);

        // anisotropic GGX alphas: aspect = sqrt(w); r2/aspect = r2*rsq(w)
        const float r2 = fast_sqrt(rough);
        const float w  = 1.0f - 0.9f * anis;
        const float alpha_u = fmaxf(r2 * fast_rsq(w),  1e-4f);
        const float alpha_v = fmaxf(r2 * fast_sqrt(w), 1e-4f);

        // fresnel_dielectric(cos, 1.5)
        const float scale  = (cosv > 0.0f) ? (1.0f / ETA_C) : ETA_C;
        const float ct_sqr = 1.0f - (1.0f - c2) * scale * scale;
        const float ctf = fast_sqrt(ct_sqr);
        const float rs  = (ci - ETA_C * ctf) * fast_rcp(ci + ETA_C * ctf);
        const float rp  = (ETA_C * ci - ctf) * fast_rcp(ETA_C * ci + ctf);
        const float f_die = 0.5f * (rs * rs + rp * rp);

        // D term (module passes eta as alpha; preserved).
        const float a2 = ETA_C * ETA_C;
        const float root_d = c2 + (1.0f - c2) * (1.0f / (a2 + 1e-10f));
        const float d_den  = PI_F * a2 * root_d * root_d + 1e-10f;

        // G term: smith_g1(cos, alpha_u) * smith_g1(cos, alpha_v)
        const float sin_t = fast_sqrt(fmaxf(1.0f - c2, 0.0f));
        const float tan_t = sin_t * fast_rcp(cosv + 1e-10f);
        const float ru  = alpha_u * tan_t;
        const float rw  = alpha_v * tan_t;
        const float g_u = 2.0f * fast_rcp(1.0f + fast_sqrt(ru * ru + 1.0f));
        const float g_v = 2.0f * fast_rcp(1.0f + fast_sqrt(rw * rw + 1.0f));
        const float g_spec = g_u * g_v;

        const float intensity = light * fast_rcp(dist[j] * dist[j] + 1e-10f);
        const float lum = intensity;
        const float eta_it = (cosv > 0.0f) ? ETA_C : (1.0f / ETA_C);

        // calc_schlick with eta clamped to 0.99999 -> always the val_neq1 branch
        const float eti2 = 0.99999f * 0.99999f;
        const float ct_s = fast_sqrt(1.0f - (1.0f - c2) * eti2);
        const float sw_ct = schlick_w(ct_s);

        float f0s = (eta_it - 1.0f) * fast_rcp(eta_it + 1.0f);
        f0s = f0s * f0s;  // == 0.04 for both branches

        // diffuse + retro-reflection
        const float fw = schlick_w(ci);
        float f_diff = 1.0f - 0.5f * fw;
        f_diff *= f_diff;
        const float alpha_d = 1.0f - rough;
        const float rr = 2.0f * alpha_d * c2;
        const float f_retro = rr * (2.0f * fw + fw * fw * (rr - 1.0f));
        const float one_m_met = 1.0f - met;
        const float diff_com = one_m_met * ci * (1.0f / PI_F) * (f_diff + f_retro);

        // d_spec * g_spec / (4|cos|) with a single combined reciprocal
        const float spec_com = g_spec * fast_rcp(d_den * 4.0f * ci);

        const float rcp_lum = fast_rcp(lum);
        const float lum_pos = (lum > 0.0f) ? 1.0f : 0.0f;

        float o[3];
#pragma unroll
        for (int k = 0; k < 3; ++k) {
            float fs = (sw_ct * (1.0f - sa[k]) + sa[k]) * met;
            const float c_tint = lum_pos * (sa[k] * rcp_lum) + (1.0f - lum_pos);
            const float f0t = c_tint * f0s;
            fs += one_m_met * tint * (sw_ct * (1.0f - f0t) + f0t);
            const float f_princ = one_m_met * (1.0f - tint) * (f_die * sa[k]) + fs;
            o[k] = f_princ * spec_com + diff_com * da[k];
        }
        ox[j] = o[0]; oy[j] = o[1]; oz[j] = o[2];
    }

    // nontemporal: output is write-once, never re-read -> don't pollute L2/L3
    f32x4* out4 = reinterpret_cast<f32x4*>(out_p) + 3 * t;
    const f32x4 o0 = {ox[0], oy[0], oz[0], ox[1]};
    const f32x4 o1 = {oy[1], oz[1], ox[2], oy[2]};
    const f32x4 o2 = {oz[2], ox[3], oy[3], oz[3]};
    __builtin_nontemporal_store(o0, out4 + 0);
    __builtin_nontemporal_store(o1, out4 + 1);
    __builtin_nontemporal_store(o2, out4 + 2);
}

}  // namespace

extern "C" void kernel_launch(void* const* d_in, const int* in_sizes, int n_in,
                              void* d_out, int out_size, void* d_ws, size_t ws_size,
                              hipStream_t stream) {
    (void)n_in; (void)out_size; (void)d_ws; (void)ws_size;
    // input order per setup_inputs():
    // 0 light(1) 1 distance(N) 2 normal(N,3) 3 viewdir(N,3) 4 anisotropic(N)
    // 5 specular_roughness(N) 6 metallic(N) 7 clearcoat(N, UNUSED)
    // 8 spec_tint(N) 9 specular_albedo(N,3) 10 diffuse_albedo(N,3)
    const float* light_p = (const float*)d_in[0];
    const float* dist_p  = (const float*)d_in[1];
    const float* norm_p  = (const float*)d_in[2];
    const float* view_p  = (const float*)d_in[3];
    const float* anis_p  = (const float*)d_in[4];
    const float* rough_p = (const float*)d_in[5];
    const float* met_p   = (const float*)d_in[6];
    const float* tint_p  = (const float*)d_in[8];
    const float* salb_p  = (const float*)d_in[9];
    const float* dalb_p  = (const float*)d_in[10];
    float* out_p = (float*)d_out;

    const int n_pts = in_sizes[1];          // N = 2,097,152 (divisible by 4*BLOCK)
    const int n_thr = (n_pts + 3) / 4;
    const int grid  = (n_thr + BLOCK - 1) / BLOCK;

    renderer_kernel<<<grid, BLOCK, 0, stream>>>(
        light_p, dist_p, norm_p, view_p, anis_p, rough_p, met_p, tint_p,
        salb_p, dalb_p, out_p, n_pts);
}

// Round 5
// 33.690 us; speedup vs baseline: 1.4397x; 1.4397x over previous
//
#include <hip/hip_runtime.h>

namespace {

constexpr float ETA_C = 1.5f;
constexpr float PI_F  = 3.14159265358979323846f;
constexpr int   BLOCK = 256;

typedef float f32x4 __attribute__((ext_vector_type(4)));  // native vector for nontemporal builtins

__device__ __forceinline__ float fast_rcp(float x)  { return __builtin_amdgcn_rcpf(x); }
__device__ __forceinline__ float fast_sqrt(float x) { return __builtin_amdgcn_sqrtf(x); }
__device__ __forceinline__ float fast_rsq(float x)  { return __builtin_amdgcn_rsqf(x); }

__device__ __forceinline__ float schlick_w(float c) {
    float m = fminf(fmaxf(1.0f - c, 0.0f), 1.0f);
    float m2 = m * m;
    return m2 * m2 * m;  // m^5
}

// (256,4): VGPR cap 128. The cap alone did NOT raise VGPR (R4: allocator chose
// 36 and serialized loads into ~5 wait batches). The sched_barrier(0) below is
// the actual lever: forces all 12 loads issued before any compute.
__global__ __launch_bounds__(BLOCK, 4) void renderer_kernel(
    const float* __restrict__ light_p,
    const float* __restrict__ dist_p,
    const float* __restrict__ norm_p,
    const float* __restrict__ view_p,
    const float* __restrict__ anis_p,
    const float* __restrict__ rough_p,
    const float* __restrict__ met_p,
    const float* __restrict__ tint_p,
    const float* __restrict__ salb_p,
    const float* __restrict__ dalb_p,
    float* __restrict__ out_p,
    int n_pts)
{
    const int t = blockIdx.x * BLOCK + threadIdx.x;   // one thread = 4 points
    if (t * 4 >= n_pts) return;

    // ---- vectorized loads: 4 points per thread, all float4-aligned ----
    const f32x4 dv = reinterpret_cast<const f32x4*>(dist_p)[t];
    const f32x4 av = reinterpret_cast<const f32x4*>(anis_p)[t];
    const f32x4 rv = reinterpret_cast<const f32x4*>(rough_p)[t];
    const f32x4 mv = reinterpret_cast<const f32x4*>(met_p)[t];
    const f32x4 tv = reinterpret_cast<const f32x4*>(tint_p)[t];

    const f32x4* n4 = reinterpret_cast<const f32x4*>(norm_p) + 3 * t;
    const f32x4 n0 = n4[0], n1 = n4[1], n2 = n4[2];
    const f32x4* v4 = reinterpret_cast<const f32x4*>(view_p) + 3 * t;
    const f32x4 v0 = v4[0], v1 = v4[1], v2 = v4[2];
    const f32x4* s4 = reinterpret_cast<const f32x4*>(salb_p) + 3 * t;
    const f32x4 s0 = s4[0], s1 = s4[1], s2 = s4[2];
    const f32x4* b4 = reinterpret_cast<const f32x4*>(dalb_p) + 3 * t;
    const f32x4 b0 = b4[0], b1 = b4[1], b2 = b4[2];

    const float light = light_p[0];

    // Hard scheduling fence: every load above must be ISSUED before any
    // compute below. Makes all 12 vmem results simultaneously live ->
    // one exposed HBM latency per wave instead of ~5 register-pressure-
    // driven load/wait batches (R4: VGPR=36, VALUBusy 11%, latency-bound).
    __builtin_amdgcn_sched_barrier(0);

    const float dist[4]  = {dv.x, dv.y, dv.z, dv.w};
    const float anv[4]   = {av.x, av.y, av.z, av.w};
    const float rgv[4]   = {rv.x, rv.y, rv.z, rv.w};
    const float mtv[4]   = {mv.x, mv.y, mv.z, mv.w};
    const float ttv[4]   = {tv.x, tv.y, tv.z, tv.w};

    const float nx[4] = {n0.x, n0.w, n1.z, n2.y};
    const float ny[4] = {n0.y, n1.x, n1.w, n2.z};
    const float nz[4] = {n0.z, n1.y, n2.x, n2.w};
    const float vx[4] = {v0.x, v0.w, v1.z, v2.y};
    const float vy[4] = {v0.y, v1.x, v1.w, v2.z};
    const float vz[4] = {v0.z, v1.y, v2.x, v2.w};
    const float sx[4] = {s0.x, s0.w, s1.z, s2.y};
    const float sy[4] = {s0.y, s1.x, s1.w, s2.z};
    const float sz[4] = {s0.z, s1.y, s2.x, s2.w};
    const float bx[4] = {b0.x, b0.w, b1.z, b2.y};
    const float by[4] = {b0.y, b1.x, b1.w, b2.z};
    const float bz[4] = {b0.z, b1.y, b2.x, b2.w};

    float ox[4], oy[4], oz[4];

#pragma unroll
    for (int j = 0; j < 4; ++j) {
        const float cosv = nx[j] * vx[j] + ny[j] * vy[j] + nz[j] * vz[j];
        const float anis  = fmaxf(anv[j], 1e-5f);
        const float rough = fmaxf(rgv[j], 1e-5f);
        const float met   = fmaxf(mtv[j], 1e-5f);
        const float tint  = fmaxf(ttv[j], 1e-6f);
        const float sa[3] = {fmaxf(sx[j], 1e-5f), fmaxf(sy[j], 1e-5f), fmaxf(sz[j], 1e-5f)};
        const float da[3] = {fmaxf(bx[j], 1e-5f), fmaxf(by[j], 1e-5f), fmaxf(bz[j], 1e-5f)};

        const float c2 = cosv * cosv;
        const float ci = fabsf(cosv);

        // anisotropic GGX alphas: aspect = sqrt(w); r2/aspect = r2*rsq(w)
        const float r2 = fast_sqrt(rough);
        const float w  = 1.0f - 0.9f * anis;
        const float alpha_u = fmaxf(r2 * fast_rsq(w),  1e-4f);
        const float alpha_v = fmaxf(r2 * fast_sqrt(w), 1e-4f);

        // fresnel_dielectric(cos, 1.5)
        const float scale  = (cosv > 0.0f) ? (1.0f / ETA_C) : ETA_C;
        const float ct_sqr = 1.0f - (1.0f - c2) * scale * scale;
        const float ctf = fast_sqrt(ct_sqr);
        const float rs  = (ci - ETA_C * ctf) * fast_rcp(ci + ETA_C * ctf);
        const float rp  = (ETA_C * ci - ctf) * fast_rcp(ETA_C * ci + ctf);
        const float f_die = 0.5f * (rs * rs + rp * rp);

        // D term (module passes eta as alpha; preserved).
        const float a2 = ETA_C * ETA_C;
        const float root_d = c2 + (1.0f - c2) * (1.0f / (a2 + 1e-10f));
        const float d_den  = PI_F * a2 * root_d * root_d + 1e-10f;

        // G term: smith_g1(cos, alpha_u) * smith_g1(cos, alpha_v)
        const float sin_t = fast_sqrt(fmaxf(1.0f - c2, 0.0f));
        const float tan_t = sin_t * fast_rcp(cosv + 1e-10f);
        const float ru  = alpha_u * tan_t;
        const float rw  = alpha_v * tan_t;
        const float g_u = 2.0f * fast_rcp(1.0f + fast_sqrt(ru * ru + 1.0f));
        const float g_v = 2.0f * fast_rcp(1.0f + fast_sqrt(rw * rw + 1.0f));
        const float g_spec = g_u * g_v;

        const float intensity = light * fast_rcp(dist[j] * dist[j] + 1e-10f);
        const float lum = intensity;
        const float eta_it = (cosv > 0.0f) ? ETA_C : (1.0f / ETA_C);

        // calc_schlick with eta clamped to 0.99999 -> always the val_neq1 branch
        const float eti2 = 0.99999f * 0.99999f;
        const float ct_s = fast_sqrt(1.0f - (1.0f - c2) * eti2);
        const float sw_ct = schlick_w(ct_s);

        float f0s = (eta_it - 1.0f) * fast_rcp(eta_it + 1.0f);
        f0s = f0s * f0s;  // == 0.04 for both branches

        // diffuse + retro-reflection
        const float fw = schlick_w(ci);
        float f_diff = 1.0f - 0.5f * fw;
        f_diff *= f_diff;
        const float alpha_d = 1.0f - rough;
        const float rr = 2.0f * alpha_d * c2;
        const float f_retro = rr * (2.0f * fw + fw * fw * (rr - 1.0f));
        const float one_m_met = 1.0f - met;
        const float diff_com = one_m_met * ci * (1.0f / PI_F) * (f_diff + f_retro);

        // d_spec * g_spec / (4|cos|) with a single combined reciprocal
        const float spec_com = g_spec * fast_rcp(d_den * 4.0f * ci);

        const float rcp_lum = fast_rcp(lum);
        const float lum_pos = (lum > 0.0f) ? 1.0f : 0.0f;

        float o[3];
#pragma unroll
        for (int k = 0; k < 3; ++k) {
            float fs = (sw_ct * (1.0f - sa[k]) + sa[k]) * met;
            const float c_tint = lum_pos * (sa[k] * rcp_lum) + (1.0f - lum_pos);
            const float f0t = c_tint * f0s;
            fs += one_m_met * tint * (sw_ct * (1.0f - f0t) + f0t);
            const float f_princ = one_m_met * (1.0f - tint) * (f_die * sa[k]) + fs;
            o[k] = f_princ * spec_com + diff_com * da[k];
        }
        ox[j] = o[0]; oy[j] = o[1]; oz[j] = o[2];
    }

    // nontemporal: output is write-once, never re-read -> don't pollute L2/L3
    f32x4* out4 = reinterpret_cast<f32x4*>(out_p) + 3 * t;
    const f32x4 o0 = {ox[0], oy[0], oz[0], ox[1]};
    const f32x4 o1 = {oy[1], oz[1], ox[2], oy[2]};
    const f32x4 o2 = {oz[2], ox[3], oy[3], oz[3]};
    __builtin_nontemporal_store(o0, out4 + 0);
    __builtin_nontemporal_store(o1, out4 + 1);
    __builtin_nontemporal_store(o2, out4 + 2);
}

}  // namespace

extern "C" void kernel_launch(void* const* d_in, const int* in_sizes, int n_in,
                              void* d_out, int out_size, void* d_ws, size_t ws_size,
                              hipStream_t stream) {
    (void)n_in; (void)out_size; (void)d_ws; (void)ws_size;
    // input order per setup_inputs():
    // 0 light(1) 1 distance(N) 2 normal(N,3) 3 viewdir(N,3) 4 anisotropic(N)
    // 5 specular_roughness(N) 6 metallic(N) 7 clearcoat(N, UNUSED)
    // 8 spec_tint(N) 9 specular_albedo(N,3) 10 diffuse_albedo(N,3)
    const float* light_p = (const float*)d_in[0];
    const float* dist_p  = (const float*)d_in[1];
    const float* norm_p  = (const float*)d_in[2];
    const float* view_p  = (const float*)d_in[3];
    const float* anis_p  = (const float*)d_in[4];
    const float* rough_p = (const float*)d_in[5];
    const float* met_p   = (const float*)d_in[6];
    const float* tint_p  = (const float*)d_in[8];
    const float* salb_p  = (const float*)d_in[9];
    const float* dalb_p  = (const float*)d_in[10];
    float* out_p = (float*)d_out;

    const int n_pts = in_sizes[1];          // N = 2,097,152 (divisible by 4*BLOCK)
    const int n_thr = (n_pts + 3) / 4;
    const int grid  = (n_thr + BLOCK - 1) / BLOCK;

    renderer_kernel<<<grid, BLOCK, 0, stream>>>(
        light_p, dist_p, norm_p, view_p, anis_p, rough_p, met_p, tint_p,
        salb_p, dalb_p, out_p, n_pts);
}